// Round 17
// baseline (266.136 us; speedup 1.0000x reference)
//
#include <hip/hip_runtime.h>
#include <hip/hip_bf16.h>

typedef unsigned short u16;
typedef unsigned int   u32;
typedef __attribute__((ext_vector_type(8))) short short8;
typedef __attribute__((ext_vector_type(4))) float floatx4;
typedef __attribute__((ext_vector_type(4))) unsigned short u16x4;

__device__ __forceinline__ u16 f2bf(float f){
  u32 x = __float_as_uint(f);
  u32 r = (x + 0x7fffu + ((x >> 16) & 1u)) >> 16;   // RNE
  return (u16)r;
}
__device__ __forceinline__ float bf2f(u16 u){
  return __uint_as_float(((u32)u) << 16);
}
// fast tanh: (e-1)/(e+1), e = 2^(2x*log2e). |err| < ~1e-5, invisible in bf16.
__device__ __forceinline__ float tanh_fast(float x){
  float xs = fminf(fmaxf(x, -16.f), 16.f);
  float e  = __builtin_amdgcn_exp2f(xs * 2.8853900817779268f);
  return (e - 1.f) * __builtin_amdgcn_rcpf(e + 1.f);
}
// async global->LDS, 16B per lane; LDS dest is wave-uniform base + lane*16
__device__ __forceinline__ void gload16(const void* g, void* l){
  __builtin_amdgcn_global_load_lds(
      (const __attribute__((address_space(1))) unsigned int*)g,
      (__attribute__((address_space(3))) unsigned int*)l, 16, 0, 0);
}

// B=64, L=1000, D=300 padded to 320; V=50000
// ---------------- K1: FUSED gather + bf16 cast + s2/s4/s10 segment sums -----
__global__ void k_gather_seg(const int* __restrict__ idx, const float* __restrict__ emb,
                             u16* __restrict__ x, u16* __restrict__ s2,
                             u16* __restrict__ s4, u16* __restrict__ s10, int total){
  int i = blockIdx.x * blockDim.x + threadIdx.x;
  if (i >= total) return;
  int d4 = i % 80; int rest = i / 80; int w = rest % 50; int b = rest / 50;
  const int dcol = d4 * 4;
  const int r0 = b * 1000 + w * 20;
  float a2[4] = {0,0,0,0}, a4[4] = {0,0,0,0}, a10[4] = {0,0,0,0};
  #pragma unroll
  for (int j = 0; j < 20; j++){
    const int r = r0 + j;
    u16x4 o; o[0] = 0; o[1] = 0; o[2] = 0; o[3] = 0;
    if (d4 < 75){
      const float4 v = *(const float4*)(emb + (size_t)idx[r] * 300 + dcol);
      o[0] = f2bf(v.x); o[1] = f2bf(v.y); o[2] = f2bf(v.z); o[3] = f2bf(v.w);
      a2[0] += v.x; a2[1] += v.y; a2[2] += v.z; a2[3] += v.w;
      a4[0] += v.x; a4[1] += v.y; a4[2] += v.z; a4[3] += v.w;
      a10[0] += v.x; a10[1] += v.y; a10[2] += v.z; a10[3] += v.w;
    }
    *(u16x4*)(x + (size_t)r * 320 + dcol) = o;
    if (j & 1){
      u16x4 s;
      #pragma unroll
      for (int q = 0; q < 4; q++){ s[q] = f2bf(a2[q]); a2[q] = 0.f; }
      *(u16x4*)(s2 + ((size_t)(b * 500 + w * 10 + (j >> 1)) * 320 + dcol)) = s;
    }
    if ((j & 3) == 3){
      u16x4 s;
      #pragma unroll
      for (int q = 0; q < 4; q++){ s[q] = f2bf(a4[q]); a4[q] = 0.f; }
      *(u16x4*)(s4 + ((size_t)(b * 250 + w * 5 + (j >> 2)) * 320 + dcol)) = s;
    }
    if (j == 9 || j == 19){
      u16x4 s;
      #pragma unroll
      for (int q = 0; q < 4; q++){ s[q] = f2bf(a10[q]); a10[q] = 0.f; }
      *(u16x4*)(s10 + ((size_t)(b * 100 + w * 2 + j / 10) * 320 + dcol)) = s;
    }
  }
}

// ---------------- K2: s25 from x --------------------------------------------
__global__ void k_s25(const u16* __restrict__ x, u16* __restrict__ s25, int total){
  int i = blockIdx.x * blockDim.x + threadIdx.x;
  if (i >= total) return;
  int d4 = i % 80; int rest = i / 80; int g = rest % 40; int b = rest / 40;
  const int dcol = d4 * 4;
  const u16* src = x + ((size_t)(b * 1000 + g * 25) * 320 + dcol);
  float a[4] = {0,0,0,0};
  #pragma unroll
  for (int j = 0; j < 25; j++){
    u16x4 v = *(const u16x4*)(src + (size_t)j * 320);
    #pragma unroll
    for (int q = 0; q < 4; q++) a[q] += bf2f(v[q]);
  }
  u16x4 o;
  #pragma unroll
  for (int q = 0; q < 4; q++) o[q] = f2bf(a[q]);
  *(u16x4*)(s25 + ((size_t)(b * 40 + g) * 320 + dcol)) = o;
}

// ---------------- K3: pack weights transposed+padded: wT[mat][n*320+k] ------
__global__ void k_wprep(const float* __restrict__ wce, const float* __restrict__ wz,
                        const float* __restrict__ wo, u16* __restrict__ wT, int total){
  int i = blockIdx.x * blockDim.x + threadIdx.x;
  if (i >= total) return;
  int mat = i / 102400; int rem = i - mat * 102400;
  int n = rem / 320;    int k = rem - n * 320;
  float v = 0.f;
  if (n < 300 && k < 300){
    const float* src = (mat < 5) ? (wce + mat * 90000) : (mat == 5 ? wz : wo);
    v = src[k * 300 + n];
  }
  wT[i] = f2bf(v);
}

// ---------------- K4: ALL GEMMs — r5 shell, DOUBLED wave tile (128x80) ------
// C[M,300] = post(A[M,320] @ W).  Block = 512 thr (8 waves 2Mx4N), tile
// 256x320, K-step 64 (5 iters), wave tile 128x80 (acc 8x5 = 160 VGPR).
// GRID FIX vs r16: 250 trios need ceil(250/8)*8*3 = 768 blocks (j in [0,96))
// so trios T=248,249 get all three members; T>=250 guard absorbs overshoot.
// __launch_bounds__(512,1): allocator free up to ~256 VGPR/wave (r7's (,2)
// spill trap avoided); 147KB LDS -> 1 block/CU regardless.  af in 4-frag
// halves caps live regs.  Staging/swizzles/epilogue are r5's verbatim.
__global__ __launch_bounds__(512, 1) void k_gemm_all(
    const u16* __restrict__ x,  const u16* __restrict__ s2,
    const u16* __restrict__ s4, const u16* __restrict__ s10,
    const u16* __restrict__ s25,const u16* __restrict__ wT,
    u16* __restrict__ t0, u16* __restrict__ t1, u16* __restrict__ t2,
    u16* __restrict__ t3, u16* __restrict__ t4,
    u16* __restrict__ zb, u16* __restrict__ ob,
    const float* __restrict__ b_ce, const float* __restrict__ bz,
    const float* __restrict__ bo)
{
  // [A0:32768][A1:32768][B0:40960][B1:40960] = 147456 B
  __shared__ __align__(16) char lds[147456];

  const int bid = blockIdx.x;
  const u16 *A, *BT; u16* C; const float* bias;
  int mode; float scale; long tileRow, Mrows;
  if (bid < 768){                  // t0/z/o trios, XCD-grouped (x L2-shared)
    const int xcd = bid & 7, j = bid >> 3;       // j in [0,96)
    const int T = (j / 3) * 8 + xcd, m = j % 3;  // T in [0,256)
    if (T >= 250) return;
    tileRow = (long)T * 256; A = x; Mrows = 64000;
    if (m == 0)      { BT = wT;              C = t0; bias = b_ce; mode = 0; scale = 1.f; }
    else if (m == 1) { BT = wT + 5 * 102400; C = zb; bias = bz;   mode = 1; scale = 1.f; }
    else             { BT = wT + 6 * 102400; C = ob; bias = bo;   mode = 1; scale = 1.f; }
  } else {
    const int g = bid - 768;
    if (g < 125)      { A=s2;  BT=wT+1*102400; C=t1; bias=b_ce+300;  mode=0; scale=0.5f;  tileRow=(long)g*256;       Mrows=32000; }
    else if (g < 188) { A=s4;  BT=wT+2*102400; C=t2; bias=b_ce+600;  mode=0; scale=0.25f; tileRow=(long)(g-125)*256; Mrows=16000; }
    else if (g < 213) { A=s10; BT=wT+3*102400; C=t3; bias=b_ce+900;  mode=0; scale=0.1f;  tileRow=(long)(g-188)*256; Mrows=6400; }
    else              { A=s25; BT=wT+4*102400; C=t4; bias=b_ce+1200; mode=0; scale=0.04f; tileRow=(long)(g-213)*256; Mrows=2560; }
  }

  const int tid  = threadIdx.x;
  const int lane = tid & 63;
  const int wid  = tid >> 6;
  const int wr   = wid >> 2;     // 0..1  (128-row half)
  const int wc   = wid & 3;      // 0..3  (80-col group)
  const int L    = lane & 15;

  // ---- staging source addrs (pre-swizzled) + wave-uniform LDS dest offs ----
  // A tile: 256 rows x 8 chunks (chunk=16B=8 K-elems); idx = l*512+tid
  const u16* aSrc[4]; int aDst[4];
  #pragma unroll
  for (int l = 0; l < 4; l++){
    const int idx = l * 512 + tid, row = idx >> 3, c = idx & 7;
    aSrc[l] = A + (tileRow + row) * 320 + ((c ^ (row & 7)) << 3);
    aDst[l] = (l * 512 + wid * 64) * 16;
  }
  // B tile: 320 cols x 8 chunks
  const u16* bSrc[5]; int bDst[5];
  #pragma unroll
  for (int l = 0; l < 5; l++){
    const int idx = l * 512 + tid, col = idx >> 3, c = idx & 7;
    bSrc[l] = BT + col * 320 + ((c ^ (col & 7)) << 3);
    bDst[l] = (l * 512 + wid * 64) * 16;
  }

  // ---- frag read offsets (with matching XOR swizzle; row&7 == L&7) ----
  const int rA  = wr * 128 + L;               // row within A tile
  const int cBt = wc * 80 + L;                // col within B tile
  int ksw[2];
  #pragma unroll
  for (int s = 0; s < 2; s++)
    ksw[s] = ((s * 4 + (lane >> 4)) ^ (lane & 7)) << 4;

  floatx4 acc[8][5];
  #pragma unroll
  for (int m = 0; m < 8; m++)
    #pragma unroll
    for (int n = 0; n < 5; n++)
      #pragma unroll
      for (int q = 0; q < 4; q++) acc[m][n][q] = 0.f;

  #define STAGE(t, nb) do {                                                     \
    _Pragma("unroll")                                                           \
    for (int l = 0; l < 4; l++)                                                 \
      gload16(aSrc[l] + (t) * 64, lds + (nb) * 32768 + aDst[l]);                \
    _Pragma("unroll")                                                           \
    for (int l = 0; l < 5; l++)                                                 \
      gload16(bSrc[l] + (t) * 64, lds + 65536 + (nb) * 40960 + bDst[l]);        \
  } while (0)

  // ---- prologue: stage tile 0 ----
  STAGE(0, 0);
  __syncthreads();

  #pragma unroll
  for (int t = 0; t < 5; t++){
    const int cur = t & 1;
    if (t < 4) STAGE(t + 1, cur ^ 1);   // next-tile DMA into the other buffer
    const char* bA = lds + cur * 32768;
    const char* bB = lds + 65536 + cur * 40960;
    #pragma unroll
    for (int s = 0; s < 2; s++){
      short8 bf[5];
      #pragma unroll
      for (int n = 0; n < 5; n++)
        bf[n] = *(const short8*)(bB + (cBt + n * 16) * 128 + ksw[s]);
      #pragma unroll
      for (int h = 0; h < 2; h++){      // af in 4-frag halves: caps live regs
        short8 af[4];
        #pragma unroll
        for (int mm = 0; mm < 4; mm++)
          af[mm] = *(const short8*)(bA + (rA + (h * 4 + mm) * 16) * 128 + ksw[s]);
        #pragma unroll
        for (int mm = 0; mm < 4; mm++)
          #pragma unroll
          for (int n = 0; n < 5; n++)
            acc[h * 4 + mm][n] = __builtin_amdgcn_mfma_f32_16x16x32_bf16(af[mm], bf[n], acc[h * 4 + mm][n], 0, 0, 0);
      }
    }
    __syncthreads();              // drains vmcnt(0): stage(t+1) landed long ago
  }
  #undef STAGE

  // ---- epilogue: D[row][col]: col = lane&15, row = (lane>>4)*4 + reg ----
  const int colbase = wc * 80 + L;
  const long rowb   = tileRow + wr * 128 + ((lane >> 4) << 2);
  #pragma unroll
  for (int m = 0; m < 8; m++){
    #pragma unroll
    for (int n = 0; n < 5; n++){
      const int gcol = colbase + n * 16;
      if (gcol < 300){
        const float bv = bias[gcol];
        #pragma unroll
        for (int r = 0; r < 4; r++){
          const long grow = rowb + m * 16 + r;
          if (grow < Mrows){
            float v = acc[m][n][r];
            v = (mode == 0) ? (fmaxf(v, 0.f) + bv) * scale : tanh_fast(v) + bv;
            C[grow * 300 + gcol] = f2bf(v);
          }
        }
      }
    }
  }
}

// ---------------- gate MLP helper -------------------------------------------
__device__ __forceinline__ float gate_eval(
    float p0, float p1, float p2, float p3, float p4,
    const float W1[3][5], const float W2[3], const float B1[3], float B2)
{
  float acc2 = B2;
  #pragma unroll
  for (int t = 0; t < 3; t++){
    float u = W1[t][0]*p0 + W1[t][1]*p1 + W1[t][2]*p2 + W1[t][3]*p3 + W1[t][4]*p4 + B1[t];
    acc2 += W2[t] * fmaxf(u, 0.f);
  }
  return fmaxf(acc2, 0.f);
}

// ---------------- S1: per-chunk scan composites (40 chunks of 25) -----------
__global__ void k_scan1(const u16* __restrict__ t0, const u16* __restrict__ t1,
    const u16* __restrict__ t2, const u16* __restrict__ t3, const u16* __restrict__ t4,
    const u16* __restrict__ z,
    const float* __restrict__ w1, const float* __restrict__ b1,
    const float* __restrict__ w2, const float* __restrict__ b2,
    float* __restrict__ cA, float* __restrict__ cB, int total)
{
  int i = blockIdx.x * blockDim.x + threadIdx.x;
  if (i >= total) return;
  int d4 = i % 75; int rest = i / 75; int ch = rest % 40; int b = rest / 40;
  const int d = d4 * 4;
  float W1[3][5], W2[3], B1[3][4], B2[4];
  #pragma unroll
  for (int t = 0; t < 3; t++){
    #pragma unroll
    for (int s = 0; s < 5; s++) W1[t][s] = w1[t * 5 + s];
    W2[t] = w2[t];
    #pragma unroll
    for (int q = 0; q < 4; q++) B1[t][q] = b1[t * 300 + d + q];
  }
  #pragma unroll
  for (int q = 0; q < 4; q++) B2[q] = b2[d + q];
  float Ac[4] = {1.f,1.f,1.f,1.f}, Bc[4] = {0.f,0.f,0.f,0.f};
  const int l0 = ch * 25;
  const u16x4 v4 = *(const u16x4*)(t4 + (size_t)(b * 40 + ch) * 300 + d);  // l/25 == ch
  for (int l = l0; l < l0 + 25; l++){
    u16x4 v0 = *(const u16x4*)(t0 + (size_t)(b * 1000 + l)        * 300 + d);
    u16x4 v1 = *(const u16x4*)(t1 + (size_t)(b * 500  + (l >> 1)) * 300 + d);
    u16x4 v2 = *(const u16x4*)(t2 + (size_t)(b * 250  + (l >> 2)) * 300 + d);
    u16x4 v3 = *(const u16x4*)(t3 + (size_t)(b * 100  + l / 10)   * 300 + d);
    u16x4 vz = *(const u16x4*)(z  + (size_t)(b * 1000 + l)        * 300 + d);
    #pragma unroll
    for (int q = 0; q < 4; q++){
      float B1q[3] = {B1[0][q], B1[1][q], B1[2][q]};
      float g  = gate_eval(bf2f(v0[q]), bf2f(v1[q]), bf2f(v2[q]), bf2f(v3[q]), bf2f(v4[q]),
                           W1, W2, B1q, B2[q]);
      Ac[q] = g * Ac[q];
      Bc[q] = g * Bc[q] + (1.f - g) * bf2f(vz[q]);
    }
  }
  *(float4*)(cA + (size_t)ch * 19200 + b * 300 + d) = make_float4(Ac[0], Ac[1], Ac[2], Ac[3]);
  *(float4*)(cB + (size_t)ch * 19200 + b * 300 + d) = make_float4(Bc[0], Bc[1], Bc[2], Bc[3]);
}

// ---------------- S2: combine 40 chunk composites -> chunk-initial c --------
__global__ void k_scan2(const float* __restrict__ cA, const float* __restrict__ cB,
                        float* __restrict__ cinit, int total){
  int i = blockIdx.x * blockDim.x + threadIdx.x;
  if (i >= total) return;
  float c = 0.f;
  for (int ch = 0; ch < 40; ch++){
    cinit[ch * 19200 + i] = c;
    c = cA[ch * 19200 + i] * c + cB[ch * 19200 + i];
  }
}

// ---------------- S3: final scan + output h = o*c ---------------------------
__global__ void k_scan3(const u16* __restrict__ t0, const u16* __restrict__ t1,
    const u16* __restrict__ t2, const u16* __restrict__ t3, const u16* __restrict__ t4,
    const u16* __restrict__ z, const u16* __restrict__ o,
    const float* __restrict__ cinit,
    const float* __restrict__ w1, const float* __restrict__ b1,
    const float* __restrict__ w2, const float* __restrict__ b2,
    float* __restrict__ out, int total)
{
  int i = blockIdx.x * blockDim.x + threadIdx.x;
  if (i >= total) return;
  int d4 = i % 75; int rest = i / 75; int ch = rest % 40; int b = rest / 40;
  const int d = d4 * 4;
  float W1[3][5], W2[3], B1[3][4], B2[4];
  #pragma unroll
  for (int t = 0; t < 3; t++){
    #pragma unroll
    for (int s = 0; s < 5; s++) W1[t][s] = w1[t * 5 + s];
    W2[t] = w2[t];
    #pragma unroll
    for (int q = 0; q < 4; q++) B1[t][q] = b1[t * 300 + d + q];
  }
  #pragma unroll
  for (int q = 0; q < 4; q++) B2[q] = b2[d + q];
  float c[4];
  {
    float4 ci = *(const float4*)(cinit + (size_t)ch * 19200 + b * 300 + d);
    c[0] = ci.x; c[1] = ci.y; c[2] = ci.z; c[3] = ci.w;
  }
  const int l0 = ch * 25;
  const u16x4 v4 = *(const u16x4*)(t4 + (size_t)(b * 40 + ch) * 300 + d);
  for (int l = l0; l < l0 + 25; l++){
    u16x4 v0 = *(const u16x4*)(t0 + (size_t)(b * 1000 + l)        * 300 + d);
    u16x4 v1 = *(const u16x4*)(t1 + (size_t)(b * 500  + (l >> 1)) * 300 + d);
    u16x4 v2 = *(const u16x4*)(t2 + (size_t)(b * 250  + (l >> 2)) * 300 + d);
    u16x4 v3 = *(const u16x4*)(t3 + (size_t)(b * 100  + l / 10)   * 300 + d);
    u16x4 vz = *(const u16x4*)(z  + (size_t)(b * 1000 + l)        * 300 + d);
    u16x4 vo = *(const u16x4*)(o  + (size_t)(b * 1000 + l)        * 300 + d);
    float4 res;
    #pragma unroll
    for (int q = 0; q < 4; q++){
      float B1q[3] = {B1[0][q], B1[1][q], B1[2][q]};
      float g  = gate_eval(bf2f(v0[q]), bf2f(v1[q]), bf2f(v2[q]), bf2f(v3[q]), bf2f(v4[q]),
                           W1, W2, B1q, B2[q]);
      c[q] = g * c[q] + (1.f - g) * bf2f(vz[q]);
      ((float*)&res)[q] = bf2f(vo[q]) * c[q];
    }
    *(float4*)(out + (size_t)(b * 1000 + l) * 300 + d) = res;
  }
}

extern "C" void kernel_launch(void* const* d_in, const int* in_sizes, int n_in,
                              void* d_out, int out_size, void* d_ws, size_t ws_size,
                              hipStream_t stream){
  const int*   article = (const int*)  d_in[0];
  const float* emb     = (const float*)d_in[1];
  const float* w_ce    = (const float*)d_in[2];
  const float* b_ce    = (const float*)d_in[3];
  const float* w1      = (const float*)d_in[4];
  const float* b1      = (const float*)d_in[5];
  const float* w2      = (const float*)d_in[6];
  const float* b2      = (const float*)d_in[7];
  const float* wz      = (const float*)d_in[8];
  const float* bz      = (const float*)d_in[9];
  const float* wo      = (const float*)d_in[10];
  const float* bo      = (const float*)d_in[11];
  float* out = (float*)d_out;
  char*  ws  = (char*)d_ws;

  // workspace layout (bytes, all 256-aligned)
  u16* x    = (u16*)(ws + 0UL);          // 64000x320 bf16  = 40,960,000
  u16* s2   = (u16*)(ws + 40960000UL);   // 32000x320       = 20,480,000
  u16* s4   = (u16*)(ws + 61440000UL);   // 16000x320       = 10,240,000
  u16* s10  = (u16*)(ws + 71680000UL);   //  6400x320       =  4,096,000
  u16* s25  = (u16*)(ws + 75776000UL);   //  2560x320       =  1,638,400
  u16* wT   = (u16*)(ws + 77414400UL);   // 7x320x320       =  1,433,600
  u16* t0   = (u16*)(ws + 78848000UL);   // 64000x300       = 38,400,000
  u16* t1   = (u16*)(ws + 117248000UL);  // 32000x300       = 19,200,000
  u16* t2   = (u16*)(ws + 136448000UL);  // 16000x300       =  9,600,000
  u16* t3   = (u16*)(ws + 146048000UL);  //  6400x300       =  3,840,000
  u16* t4   = (u16*)(ws + 149888000UL);  //  2560x300       =  1,536,000
  u16* zb   = (u16*)(ws + 151424000UL);  // 64000x300       = 38,400,000
  u16* ob   = (u16*)(ws + 189824000UL);  // 64000x300       = 38,400,000
  // scan composites live in the s2 region (dead after k_gemm_all):
  float* cA = (float*)(ws + 40960000UL); // 40x19200 f32 = 3,072,000
  float* cB = (float*)(ws + 44032000UL);
  float* ci = (float*)(ws + 47104000UL);
  (void)ws_size; (void)in_sizes; (void)n_in; (void)out_size;

  k_wprep     <<<2800, 256, 0, stream>>>(w_ce, wz, wo, wT, 716800);
  k_gather_seg<<<1000, 256, 0, stream>>>(article, emb, x, s2, s4, s10, 256000);
  k_s25       <<< 800, 256, 0, stream>>>(x, s25, 204800);

  k_gemm_all<<<991, 512, 0, stream>>>(x, s2, s4, s10, s25, wT,
                                      t0, t1, t2, t3, t4, zb, ob,
                                      b_ce, bz, bo);

  k_scan1<<<750, 256, 0, stream>>>(t0, t1, t2, t3, t4, zb, w1, b1, w2, b2, cA, cB, 192000);
  k_scan2<<< 75, 256, 0, stream>>>(cA, cB, ci, 19200);
  k_scan3<<<750, 256, 0, stream>>>(t0, t1, t2, t3, t4, zb, ob, ci, w1, b1, w2, b2, out, 192000);
}

// Round 18
// 232.693 us; speedup vs baseline: 1.1437x; 1.1437x over previous
//
#include <hip/hip_runtime.h>
#include <hip/hip_bf16.h>

typedef unsigned short u16;
typedef unsigned int   u32;
typedef __attribute__((ext_vector_type(8))) short short8;
typedef __attribute__((ext_vector_type(4))) float floatx4;
typedef __attribute__((ext_vector_type(4))) unsigned short u16x4;

__device__ __forceinline__ u16 f2bf(float f){
  u32 x = __float_as_uint(f);
  u32 r = (x + 0x7fffu + ((x >> 16) & 1u)) >> 16;   // RNE
  return (u16)r;
}
__device__ __forceinline__ float bf2f(u16 u){
  return __uint_as_float(((u32)u) << 16);
}
// fast tanh: (e-1)/(e+1), e = 2^(2x*log2e). |err| < ~1e-5, invisible in bf16.
__device__ __forceinline__ float tanh_fast(float x){
  float xs = fminf(fmaxf(x, -16.f), 16.f);
  float e  = __builtin_amdgcn_exp2f(xs * 2.8853900817779268f);
  return (e - 1.f) * __builtin_amdgcn_rcpf(e + 1.f);
}
// async global->LDS, 16B per lane; LDS dest is wave-uniform base + lane*16
__device__ __forceinline__ void gload16(const void* g, void* l){
  __builtin_amdgcn_global_load_lds(
      (const __attribute__((address_space(1))) unsigned int*)g,
      (__attribute__((address_space(3))) unsigned int*)l, 16, 0, 0);
}

// B=64, L=1000, D=300 padded to 320; V=50000
// ---------------- K1: FUSED gather + bf16 cast + s2/s4/s10 segment sums -----
__global__ void k_gather_seg(const int* __restrict__ idx, const float* __restrict__ emb,
                             u16* __restrict__ x, u16* __restrict__ s2,
                             u16* __restrict__ s4, u16* __restrict__ s10, int total){
  int i = blockIdx.x * blockDim.x + threadIdx.x;
  if (i >= total) return;
  int d4 = i % 80; int rest = i / 80; int w = rest % 50; int b = rest / 50;
  const int dcol = d4 * 4;
  const int r0 = b * 1000 + w * 20;
  float a2[4] = {0,0,0,0}, a4[4] = {0,0,0,0}, a10[4] = {0,0,0,0};
  #pragma unroll
  for (int j = 0; j < 20; j++){
    const int r = r0 + j;
    u16x4 o; o[0] = 0; o[1] = 0; o[2] = 0; o[3] = 0;
    if (d4 < 75){
      const float4 v = *(const float4*)(emb + (size_t)idx[r] * 300 + dcol);
      o[0] = f2bf(v.x); o[1] = f2bf(v.y); o[2] = f2bf(v.z); o[3] = f2bf(v.w);
      a2[0] += v.x; a2[1] += v.y; a2[2] += v.z; a2[3] += v.w;
      a4[0] += v.x; a4[1] += v.y; a4[2] += v.z; a4[3] += v.w;
      a10[0] += v.x; a10[1] += v.y; a10[2] += v.z; a10[3] += v.w;
    }
    *(u16x4*)(x + (size_t)r * 320 + dcol) = o;
    if (j & 1){
      u16x4 s;
      #pragma unroll
      for (int q = 0; q < 4; q++){ s[q] = f2bf(a2[q]); a2[q] = 0.f; }
      *(u16x4*)(s2 + ((size_t)(b * 500 + w * 10 + (j >> 1)) * 320 + dcol)) = s;
    }
    if ((j & 3) == 3){
      u16x4 s;
      #pragma unroll
      for (int q = 0; q < 4; q++){ s[q] = f2bf(a4[q]); a4[q] = 0.f; }
      *(u16x4*)(s4 + ((size_t)(b * 250 + w * 5 + (j >> 2)) * 320 + dcol)) = s;
    }
    if (j == 9 || j == 19){
      u16x4 s;
      #pragma unroll
      for (int q = 0; q < 4; q++){ s[q] = f2bf(a10[q]); a10[q] = 0.f; }
      *(u16x4*)(s10 + ((size_t)(b * 100 + w * 2 + j / 10) * 320 + dcol)) = s;
    }
  }
}

// ---------------- K2: s25 from x --------------------------------------------
__global__ void k_s25(const u16* __restrict__ x, u16* __restrict__ s25, int total){
  int i = blockIdx.x * blockDim.x + threadIdx.x;
  if (i >= total) return;
  int d4 = i % 80; int rest = i / 80; int g = rest % 40; int b = rest / 40;
  const int dcol = d4 * 4;
  const u16* src = x + ((size_t)(b * 1000 + g * 25) * 320 + dcol);
  float a[4] = {0,0,0,0};
  #pragma unroll
  for (int j = 0; j < 25; j++){
    u16x4 v = *(const u16x4*)(src + (size_t)j * 320);
    #pragma unroll
    for (int q = 0; q < 4; q++) a[q] += bf2f(v[q]);
  }
  u16x4 o;
  #pragma unroll
  for (int q = 0; q < 4; q++) o[q] = f2bf(a[q]);
  *(u16x4*)(s25 + ((size_t)(b * 40 + g) * 320 + dcol)) = o;
}

// ---------------- K3: pack weights transposed+padded: wT[mat][n*320+k] ------
__global__ void k_wprep(const float* __restrict__ wce, const float* __restrict__ wz,
                        const float* __restrict__ wo, u16* __restrict__ wT, int total){
  int i = blockIdx.x * blockDim.x + threadIdx.x;
  if (i >= total) return;
  int mat = i / 102400; int rem = i - mat * 102400;
  int n = rem / 320;    int k = rem - n * 320;
  float v = 0.f;
  if (n < 300 && k < 300){
    const float* src = (mat < 5) ? (wce + mat * 90000) : (mat == 5 ? wz : wo);
    v = src[k * 300 + n];
  }
  wT[i] = f2bf(v);
}

// ---------------- K4: ALL GEMMs — r5 shell verbatim (best measured) ---------
// C[M,300] = post(A[M,320] @ W).  Block = 512 thr (8 waves 2Mx4N), tile
// 128x320, K-step 64 (5 iters), LDS 114KB double-buffered.  Best-measured
// GEMM across 12 structures (103us, WRITE 146MB, 0 conflicts, VGPR 88).
// Larger wave tiles spill (128-VGPR hard cap for 512-thr blocks: r7/r16/
// r17); deeper pipelines stall the same (r8/r13); smaller tiles
// oversubscribe LDS (r6/r10).  Staging via global_load_lds w=16, linear
// LDS dest + inverse-swizzled global source (rule 21), chunk swizzle
// c^(row&7) on 128B rows.
__global__ __launch_bounds__(512, 2) void k_gemm_all(
    const u16* __restrict__ x,  const u16* __restrict__ s2,
    const u16* __restrict__ s4, const u16* __restrict__ s10,
    const u16* __restrict__ s25,const u16* __restrict__ wT,
    u16* __restrict__ t0, u16* __restrict__ t1, u16* __restrict__ t2,
    u16* __restrict__ t3, u16* __restrict__ t4,
    u16* __restrict__ zb, u16* __restrict__ ob,
    const float* __restrict__ b_ce, const float* __restrict__ bz,
    const float* __restrict__ bo)
{
  // [A0:16384][A1:16384][B0:40960][B1:40960] = 114688 B
  __shared__ __align__(16) char lds[114688];

  const int bid = blockIdx.x;
  const u16 *A, *BT; u16* C; const float* bias;
  int mode; float scale; long tileRow;
  if (bid < 1512){                 // t0/z/o trios, XCD-grouped (x L2-shared)
    const int xcd = bid & 7, j = bid >> 3;
    const int T = (j / 3) * 8 + xcd, m = j % 3;
    if (T >= 500) return;
    tileRow = (long)T * 128; A = x;
    if (m == 0)      { BT = wT;              C = t0; bias = b_ce; mode = 0; scale = 1.f; }
    else if (m == 1) { BT = wT + 5 * 102400; C = zb; bias = bz;   mode = 1; scale = 1.f; }
    else             { BT = wT + 6 * 102400; C = ob; bias = bo;   mode = 1; scale = 1.f; }
  } else {
    const int g = bid - 1512;
    if (g < 250)      { A=s2;  BT=wT+1*102400; C=t1; bias=b_ce+300;  mode=0; scale=0.5f;  tileRow=(long)g*128; }
    else if (g < 375) { A=s4;  BT=wT+2*102400; C=t2; bias=b_ce+600;  mode=0; scale=0.25f; tileRow=(long)(g-250)*128; }
    else if (g < 425) { A=s10; BT=wT+3*102400; C=t3; bias=b_ce+900;  mode=0; scale=0.1f;  tileRow=(long)(g-375)*128; }
    else              { A=s25; BT=wT+4*102400; C=t4; bias=b_ce+1200; mode=0; scale=0.04f; tileRow=(long)(g-425)*128; }
  }

  const int tid  = threadIdx.x;
  const int lane = tid & 63;
  const int wid  = tid >> 6;
  const int wr   = wid >> 2;     // 0..1  (64-row half)
  const int wc   = wid & 3;      // 0..3  (80-col group)

  // ---- staging source addrs (pre-swizzled) + wave-uniform LDS dest offs ----
  const u16* aSrc[2]; int aDst[2];
  #pragma unroll
  for (int l = 0; l < 2; l++){
    const int idx = l * 512 + tid, row = idx >> 3, c = idx & 7;
    aSrc[l] = A + (tileRow + row) * 320 + ((c ^ (row & 7)) << 3);
    aDst[l] = (l * 512 + wid * 64) * 16;
  }
  const u16* bSrc[5]; int bDst[5];
  #pragma unroll
  for (int l = 0; l < 5; l++){
    const int idx = l * 512 + tid, col = idx >> 3, c = idx & 7;
    bSrc[l] = BT + col * 320 + ((c ^ (col & 7)) << 3);
    bDst[l] = (l * 512 + wid * 64) * 16;
  }

  // ---- frag read offsets (with matching XOR swizzle) ----
  const int rA  = wr * 64 + (lane & 15);      // row within A tile
  const int cBt = wc * 80 + (lane & 15);      // col within B tile
  int ksw[2];
  #pragma unroll
  for (int s = 0; s < 2; s++)
    ksw[s] = ((s * 4 + (lane >> 4)) ^ (lane & 7)) << 4;

  floatx4 acc[4][5];
  #pragma unroll
  for (int m = 0; m < 4; m++)
    #pragma unroll
    for (int n = 0; n < 5; n++)
      #pragma unroll
      for (int q = 0; q < 4; q++) acc[m][n][q] = 0.f;

  // ---- prologue: stage tile 0 ----
  #pragma unroll
  for (int l = 0; l < 2; l++) gload16(aSrc[l], lds + aDst[l]);
  #pragma unroll
  for (int l = 0; l < 5; l++) gload16(bSrc[l], lds + 32768 + bDst[l]);
  __syncthreads();

  #pragma unroll
  for (int t = 0; t < 5; t++){
    const int cur = t & 1;
    if (t < 4){                   // issue next-tile DMA into the other buffer
      const int nb = cur ^ 1;
      #pragma unroll
      for (int l = 0; l < 2; l++) gload16(aSrc[l] + (t + 1) * 64, lds + nb * 16384 + aDst[l]);
      #pragma unroll
      for (int l = 0; l < 5; l++) gload16(bSrc[l] + (t + 1) * 64, lds + 32768 + nb * 40960 + bDst[l]);
    }
    const char* bA = lds + cur * 16384;
    const char* bB = lds + 32768 + cur * 40960;
    #pragma unroll
    for (int s = 0; s < 2; s++){
      short8 af[4], bf[5];
      #pragma unroll
      for (int m = 0; m < 4; m++)
        af[m] = *(const short8*)(bA + (rA + m * 16) * 128 + ksw[s]);
      #pragma unroll
      for (int n = 0; n < 5; n++)
        bf[n] = *(const short8*)(bB + (cBt + n * 16) * 128 + ksw[s]);
      #pragma unroll
      for (int m = 0; m < 4; m++)
        #pragma unroll
        for (int n = 0; n < 5; n++)
          acc[m][n] = __builtin_amdgcn_mfma_f32_16x16x32_bf16(af[m], bf[n], acc[m][n], 0, 0, 0);
    }
    __syncthreads();              // drains vmcnt(0): stage(t+1) landed long ago
  }

  // ---- epilogue: D[row][col]: col = lane&15, row = (lane>>4)*4 + reg ----
  const int colbase = wc * 80 + (lane & 15);
  const long rowb   = tileRow + wr * 64 + ((lane >> 4) << 2);
  #pragma unroll
  for (int m = 0; m < 4; m++){
    #pragma unroll
    for (int n = 0; n < 5; n++){
      const int gcol = colbase + n * 16;
      if (gcol < 300){
        const float bv = bias[gcol];
        #pragma unroll
        for (int r = 0; r < 4; r++){
          const long grow = rowb + m * 16 + r;
          float v = acc[m][n][r];
          v = (mode == 0) ? (fmaxf(v, 0.f) + bv) * scale : tanh_fast(v) + bv;
          C[grow * 300 + gcol] = f2bf(v);
        }
      }
    }
  }
}

// ---------------- gate MLP helper -------------------------------------------
__device__ __forceinline__ float gate_eval(
    float p0, float p1, float p2, float p3, float p4,
    const float W1[3][5], const float W2[3], const float B1[3], float B2)
{
  float acc2 = B2;
  #pragma unroll
  for (int t = 0; t < 3; t++){
    float u = W1[t][0]*p0 + W1[t][1]*p1 + W1[t][2]*p2 + W1[t][3]*p3 + W1[t][4]*p4 + B1[t];
    acc2 += W2[t] * fmaxf(u, 0.f);
  }
  return fmaxf(acc2, 0.f);
}

// ---------------- S1: per-chunk scan composites (40 chunks of 25) -----------
__global__ void k_scan1(const u16* __restrict__ t0, const u16* __restrict__ t1,
    const u16* __restrict__ t2, const u16* __restrict__ t3, const u16* __restrict__ t4,
    const u16* __restrict__ z,
    const float* __restrict__ w1, const float* __restrict__ b1,
    const float* __restrict__ w2, const float* __restrict__ b2,
    float* __restrict__ cA, float* __restrict__ cB, int total)
{
  int i = blockIdx.x * blockDim.x + threadIdx.x;
  if (i >= total) return;
  int d4 = i % 75; int rest = i / 75; int ch = rest % 40; int b = rest / 40;
  const int d = d4 * 4;
  float W1[3][5], W2[3], B1[3][4], B2[4];
  #pragma unroll
  for (int t = 0; t < 3; t++){
    #pragma unroll
    for (int s = 0; s < 5; s++) W1[t][s] = w1[t * 5 + s];
    W2[t] = w2[t];
    #pragma unroll
    for (int q = 0; q < 4; q++) B1[t][q] = b1[t * 300 + d + q];
  }
  #pragma unroll
  for (int q = 0; q < 4; q++) B2[q] = b2[d + q];
  float Ac[4] = {1.f,1.f,1.f,1.f}, Bc[4] = {0.f,0.f,0.f,0.f};
  const int l0 = ch * 25;
  const u16x4 v4 = *(const u16x4*)(t4 + (size_t)(b * 40 + ch) * 300 + d);  // l/25 == ch
  for (int l = l0; l < l0 + 25; l++){
    u16x4 v0 = *(const u16x4*)(t0 + (size_t)(b * 1000 + l)        * 300 + d);
    u16x4 v1 = *(const u16x4*)(t1 + (size_t)(b * 500  + (l >> 1)) * 300 + d);
    u16x4 v2 = *(const u16x4*)(t2 + (size_t)(b * 250  + (l >> 2)) * 300 + d);
    u16x4 v3 = *(const u16x4*)(t3 + (size_t)(b * 100  + l / 10)   * 300 + d);
    u16x4 vz = *(const u16x4*)(z  + (size_t)(b * 1000 + l)        * 300 + d);
    #pragma unroll
    for (int q = 0; q < 4; q++){
      float B1q[3] = {B1[0][q], B1[1][q], B1[2][q]};
      float g  = gate_eval(bf2f(v0[q]), bf2f(v1[q]), bf2f(v2[q]), bf2f(v3[q]), bf2f(v4[q]),
                           W1, W2, B1q, B2[q]);
      Ac[q] = g * Ac[q];
      Bc[q] = g * Bc[q] + (1.f - g) * bf2f(vz[q]);
    }
  }
  *(float4*)(cA + (size_t)ch * 19200 + b * 300 + d) = make_float4(Ac[0], Ac[1], Ac[2], Ac[3]);
  *(float4*)(cB + (size_t)ch * 19200 + b * 300 + d) = make_float4(Bc[0], Bc[1], Bc[2], Bc[3]);
}

// ---------------- S2: combine 40 chunk composites -> chunk-initial c --------
__global__ void k_scan2(const float* __restrict__ cA, const float* __restrict__ cB,
                        float* __restrict__ cinit, int total){
  int i = blockIdx.x * blockDim.x + threadIdx.x;
  if (i >= total) return;
  float c = 0.f;
  for (int ch = 0; ch < 40; ch++){
    cinit[ch * 19200 + i] = c;
    c = cA[ch * 19200 + i] * c + cB[ch * 19200 + i];
  }
}

// ---------------- S3: final scan + output h = o*c ---------------------------
__global__ void k_scan3(const u16* __restrict__ t0, const u16* __restrict__ t1,
    const u16* __restrict__ t2, const u16* __restrict__ t3, const u16* __restrict__ t4,
    const u16* __restrict__ z, const u16* __restrict__ o,
    const float* __restrict__ cinit,
    const float* __restrict__ w1, const float* __restrict__ b1,
    const float* __restrict__ w2, const float* __restrict__ b2,
    float* __restrict__ out, int total)
{
  int i = blockIdx.x * blockDim.x + threadIdx.x;
  if (i >= total) return;
  int d4 = i % 75; int rest = i / 75; int ch = rest % 40; int b = rest / 40;
  const int d = d4 * 4;
  float W1[3][5], W2[3], B1[3][4], B2[4];
  #pragma unroll
  for (int t = 0; t < 3; t++){
    #pragma unroll
    for (int s = 0; s < 5; s++) W1[t][s] = w1[t * 5 + s];
    W2[t] = w2[t];
    #pragma unroll
    for (int q = 0; q < 4; q++) B1[t][q] = b1[t * 300 + d + q];
  }
  #pragma unroll
  for (int q = 0; q < 4; q++) B2[q] = b2[d + q];
  float c[4];
  {
    float4 ci = *(const float4*)(cinit + (size_t)ch * 19200 + b * 300 + d);
    c[0] = ci.x; c[1] = ci.y; c[2] = ci.z; c[3] = ci.w;
  }
  const int l0 = ch * 25;
  const u16x4 v4 = *(const u16x4*)(t4 + (size_t)(b * 40 + ch) * 300 + d);
  for (int l = l0; l < l0 + 25; l++){
    u16x4 v0 = *(const u16x4*)(t0 + (size_t)(b * 1000 + l)        * 300 + d);
    u16x4 v1 = *(const u16x4*)(t1 + (size_t)(b * 500  + (l >> 1)) * 300 + d);
    u16x4 v2 = *(const u16x4*)(t2 + (size_t)(b * 250  + (l >> 2)) * 300 + d);
    u16x4 v3 = *(const u16x4*)(t3 + (size_t)(b * 100  + l / 10)   * 300 + d);
    u16x4 vz = *(const u16x4*)(z  + (size_t)(b * 1000 + l)        * 300 + d);
    u16x4 vo = *(const u16x4*)(o  + (size_t)(b * 1000 + l)        * 300 + d);
    float4 res;
    #pragma unroll
    for (int q = 0; q < 4; q++){
      float B1q[3] = {B1[0][q], B1[1][q], B1[2][q]};
      float g  = gate_eval(bf2f(v0[q]), bf2f(v1[q]), bf2f(v2[q]), bf2f(v3[q]), bf2f(v4[q]),
                           W1, W2, B1q, B2[q]);
      c[q] = g * c[q] + (1.f - g) * bf2f(vz[q]);
      ((float*)&res)[q] = bf2f(vo[q]) * c[q];
    }
    *(float4*)(out + (size_t)(b * 1000 + l) * 300 + d) = res;
  }
}

extern "C" void kernel_launch(void* const* d_in, const int* in_sizes, int n_in,
                              void* d_out, int out_size, void* d_ws, size_t ws_size,
                              hipStream_t stream){
  const int*   article = (const int*)  d_in[0];
  const float* emb     = (const float*)d_in[1];
  const float* w_ce    = (const float*)d_in[2];
  const float* b_ce    = (const float*)d_in[3];
  const float* w1      = (const float*)d_in[4];
  const float* b1      = (const float*)d_in[5];
  const float* w2      = (const float*)d_in[6];
  const float* b2      = (const float*)d_in[7];
  const float* wz      = (const float*)d_in[8];
  const float* bz      = (const float*)d_in[9];
  const float* wo      = (const float*)d_in[10];
  const float* bo      = (const float*)d_in[11];
  float* out = (float*)d_out;
  char*  ws  = (char*)d_ws;

  // workspace layout (bytes, all 256-aligned)
  u16* x    = (u16*)(ws + 0UL);          // 64000x320 bf16  = 40,960,000
  u16* s2   = (u16*)(ws + 40960000UL);   // 32000x320       = 20,480,000
  u16* s4   = (u16*)(ws + 61440000UL);   // 16000x320       = 10,240,000
  u16* s10  = (u16*)(ws + 71680000UL);   //  6400x320       =  4,096,000
  u16* s25  = (u16*)(ws + 75776000UL);   //  2560x320       =  1,638,400
  u16* wT   = (u16*)(ws + 77414400UL);   // 7x320x320       =  1,433,600
  u16* t0   = (u16*)(ws + 78848000UL);   // 64000x300       = 38,400,000
  u16* t1   = (u16*)(ws + 117248000UL);  // 32000x300       = 19,200,000
  u16* t2   = (u16*)(ws + 136448000UL);  // 16000x300       =  9,600,000
  u16* t3   = (u16*)(ws + 146048000UL);  //  6400x300       =  3,840,000
  u16* t4   = (u16*)(ws + 149888000UL);  //  2560x300       =  1,536,000
  u16* zb   = (u16*)(ws + 151424000UL);  // 64000x300       = 38,400,000
  u16* ob   = (u16*)(ws + 189824000UL);  // 64000x300       = 38,400,000
  // scan composites live in the s2 region (dead after k_gemm_all):
  float* cA = (float*)(ws + 40960000UL); // 40x19200 f32 = 3,072,000
  float* cB = (float*)(ws + 44032000UL);
  float* ci = (float*)(ws + 47104000UL);
  (void)ws_size; (void)in_sizes; (void)n_in; (void)out_size;

  k_wprep     <<<2800, 256, 0, stream>>>(w_ce, wz, wo, wT, 716800);
  k_gather_seg<<<1000, 256, 0, stream>>>(article, emb, x, s2, s4, s10, 256000);
  k_s25       <<< 800, 256, 0, stream>>>(x, s25, 204800);

  k_gemm_all<<<1957, 512, 0, stream>>>(x, s2, s4, s10, s25, wT,
                                       t0, t1, t2, t3, t4, zb, ob,
                                       b_ce, bz, bo);

  k_scan1<<<750, 256, 0, stream>>>(t0, t1, t2, t3, t4, zb, w1, b1, w2, b2, cA, cB, 192000);
  k_scan2<<< 75, 256, 0, stream>>>(cA, cB, ci, 19200);
  k_scan3<<<750, 256, 0, stream>>>(t0, t1, t2, t3, t4, zb, ob, ci, w1, b1, w2, b2, out, 192000);
}

// Round 19
// 229.546 us; speedup vs baseline: 1.1594x; 1.0137x over previous
//
#include <hip/hip_runtime.h>
#include <hip/hip_bf16.h>

typedef unsigned short u16;
typedef unsigned int   u32;
typedef __attribute__((ext_vector_type(8))) short short8;
typedef __attribute__((ext_vector_type(4))) float floatx4;
typedef __attribute__((ext_vector_type(4))) unsigned short u16x4;

__device__ __forceinline__ u16 f2bf(float f){
  u32 x = __float_as_uint(f);
  u32 r = (x + 0x7fffu + ((x >> 16) & 1u)) >> 16;   // RNE
  return (u16)r;
}
__device__ __forceinline__ float bf2f(u16 u){
  return __uint_as_float(((u32)u) << 16);
}
// fast tanh: (e-1)/(e+1), e = 2^(2x*log2e). |err| < ~1e-5, invisible in bf16.
__device__ __forceinline__ float tanh_fast(float x){
  float xs = fminf(fmaxf(x, -16.f), 16.f);
  float e  = __builtin_amdgcn_exp2f(xs * 2.8853900817779268f);
  return (e - 1.f) * __builtin_amdgcn_rcpf(e + 1.f);
}
// async global->LDS, 16B per lane; LDS dest is wave-uniform base + lane*16
__device__ __forceinline__ void gload16(const void* g, void* l){
  __builtin_amdgcn_global_load_lds(
      (const __attribute__((address_space(1))) unsigned int*)g,
      (__attribute__((address_space(3))) unsigned int*)l, 16, 0, 0);
}

// B=64, L=1000, D=300 padded to 320; V=50000
// ---------------- K1: FUSED gather + bf16 cast + s2/s4/s10 segment sums -----
__global__ void k_gather_seg(const int* __restrict__ idx, const float* __restrict__ emb,
                             u16* __restrict__ x, u16* __restrict__ s2,
                             u16* __restrict__ s4, u16* __restrict__ s10, int total){
  int i = blockIdx.x * blockDim.x + threadIdx.x;
  if (i >= total) return;
  int d4 = i % 80; int rest = i / 80; int w = rest % 50; int b = rest / 50;
  const int dcol = d4 * 4;
  const int r0 = b * 1000 + w * 20;
  float a2[4] = {0,0,0,0}, a4[4] = {0,0,0,0}, a10[4] = {0,0,0,0};
  #pragma unroll
  for (int j = 0; j < 20; j++){
    const int r = r0 + j;
    u16x4 o; o[0] = 0; o[1] = 0; o[2] = 0; o[3] = 0;
    if (d4 < 75){
      const float4 v = *(const float4*)(emb + (size_t)idx[r] * 300 + dcol);
      o[0] = f2bf(v.x); o[1] = f2bf(v.y); o[2] = f2bf(v.z); o[3] = f2bf(v.w);
      a2[0] += v.x; a2[1] += v.y; a2[2] += v.z; a2[3] += v.w;
      a4[0] += v.x; a4[1] += v.y; a4[2] += v.z; a4[3] += v.w;
      a10[0] += v.x; a10[1] += v.y; a10[2] += v.z; a10[3] += v.w;
    }
    *(u16x4*)(x + (size_t)r * 320 + dcol) = o;
    if (j & 1){
      u16x4 s;
      #pragma unroll
      for (int q = 0; q < 4; q++){ s[q] = f2bf(a2[q]); a2[q] = 0.f; }
      *(u16x4*)(s2 + ((size_t)(b * 500 + w * 10 + (j >> 1)) * 320 + dcol)) = s;
    }
    if ((j & 3) == 3){
      u16x4 s;
      #pragma unroll
      for (int q = 0; q < 4; q++){ s[q] = f2bf(a4[q]); a4[q] = 0.f; }
      *(u16x4*)(s4 + ((size_t)(b * 250 + w * 5 + (j >> 2)) * 320 + dcol)) = s;
    }
    if (j == 9 || j == 19){
      u16x4 s;
      #pragma unroll
      for (int q = 0; q < 4; q++){ s[q] = f2bf(a10[q]); a10[q] = 0.f; }
      *(u16x4*)(s10 + ((size_t)(b * 100 + w * 2 + j / 10) * 320 + dcol)) = s;
    }
  }
}

// ---------------- K2: s25 from x --------------------------------------------
__global__ void k_s25(const u16* __restrict__ x, u16* __restrict__ s25, int total){
  int i = blockIdx.x * blockDim.x + threadIdx.x;
  if (i >= total) return;
  int d4 = i % 80; int rest = i / 80; int g = rest % 40; int b = rest / 40;
  const int dcol = d4 * 4;
  const u16* src = x + ((size_t)(b * 1000 + g * 25) * 320 + dcol);
  float a[4] = {0,0,0,0};
  #pragma unroll
  for (int j = 0; j < 25; j++){
    u16x4 v = *(const u16x4*)(src + (size_t)j * 320);
    #pragma unroll
    for (int q = 0; q < 4; q++) a[q] += bf2f(v[q]);
  }
  u16x4 o;
  #pragma unroll
  for (int q = 0; q < 4; q++) o[q] = f2bf(a[q]);
  *(u16x4*)(s25 + ((size_t)(b * 40 + g) * 320 + dcol)) = o;
}

// ---------------- K3: pack weights transposed+padded: wT[mat][n*320+k] ------
__global__ void k_wprep(const float* __restrict__ wce, const float* __restrict__ wz,
                        const float* __restrict__ wo, u16* __restrict__ wT, int total){
  int i = blockIdx.x * blockDim.x + threadIdx.x;
  if (i >= total) return;
  int mat = i / 102400; int rem = i - mat * 102400;
  int n = rem / 320;    int k = rem - n * 320;
  float v = 0.f;
  if (n < 300 && k < 300){
    const float* src = (mat < 5) ? (wce + mat * 90000) : (mat == 5 ? wz : wo);
    v = src[k * 300 + n];
  }
  wT[i] = f2bf(v);
}

// ---------------- K4: ALL GEMMs — r5 shell verbatim (best measured) ---------
// C[M,300] = post(A[M,320] @ W).  Block = 512 thr (8 waves 2Mx4N), tile
// 128x320, K-step 64 (5 iters), LDS 114KB double-buffered.  Best-measured
// GEMM across 12 structures (103us, WRITE 146MB, 0 conflicts, VGPR 88).
__global__ __launch_bounds__(512, 2) void k_gemm_all(
    const u16* __restrict__ x,  const u16* __restrict__ s2,
    const u16* __restrict__ s4, const u16* __restrict__ s10,
    const u16* __restrict__ s25,const u16* __restrict__ wT,
    u16* __restrict__ t0, u16* __restrict__ t1, u16* __restrict__ t2,
    u16* __restrict__ t3, u16* __restrict__ t4,
    u16* __restrict__ zb, u16* __restrict__ ob,
    const float* __restrict__ b_ce, const float* __restrict__ bz,
    const float* __restrict__ bo)
{
  // [A0:16384][A1:16384][B0:40960][B1:40960] = 114688 B
  __shared__ __align__(16) char lds[114688];

  const int bid = blockIdx.x;
  const u16 *A, *BT; u16* C; const float* bias;
  int mode; float scale; long tileRow;
  if (bid < 1512){                 // t0/z/o trios, XCD-grouped (x L2-shared)
    const int xcd = bid & 7, j = bid >> 3;
    const int T = (j / 3) * 8 + xcd, m = j % 3;
    if (T >= 500) return;
    tileRow = (long)T * 128; A = x;
    if (m == 0)      { BT = wT;              C = t0; bias = b_ce; mode = 0; scale = 1.f; }
    else if (m == 1) { BT = wT + 5 * 102400; C = zb; bias = bz;   mode = 1; scale = 1.f; }
    else             { BT = wT + 6 * 102400; C = ob; bias = bo;   mode = 1; scale = 1.f; }
  } else {
    const int g = bid - 1512;
    if (g < 250)      { A=s2;  BT=wT+1*102400; C=t1; bias=b_ce+300;  mode=0; scale=0.5f;  tileRow=(long)g*128; }
    else if (g < 375) { A=s4;  BT=wT+2*102400; C=t2; bias=b_ce+600;  mode=0; scale=0.25f; tileRow=(long)(g-250)*128; }
    else if (g < 425) { A=s10; BT=wT+3*102400; C=t3; bias=b_ce+900;  mode=0; scale=0.1f;  tileRow=(long)(g-375)*128; }
    else              { A=s25; BT=wT+4*102400; C=t4; bias=b_ce+1200; mode=0; scale=0.04f; tileRow=(long)(g-425)*128; }
  }

  const int tid  = threadIdx.x;
  const int lane = tid & 63;
  const int wid  = tid >> 6;
  const int wr   = wid >> 2;     // 0..1  (64-row half)
  const int wc   = wid & 3;      // 0..3  (80-col group)

  // ---- staging source addrs (pre-swizzled) + wave-uniform LDS dest offs ----
  const u16* aSrc[2]; int aDst[2];
  #pragma unroll
  for (int l = 0; l < 2; l++){
    const int idx = l * 512 + tid, row = idx >> 3, c = idx & 7;
    aSrc[l] = A + (tileRow + row) * 320 + ((c ^ (row & 7)) << 3);
    aDst[l] = (l * 512 + wid * 64) * 16;
  }
  const u16* bSrc[5]; int bDst[5];
  #pragma unroll
  for (int l = 0; l < 5; l++){
    const int idx = l * 512 + tid, col = idx >> 3, c = idx & 7;
    bSrc[l] = BT + col * 320 + ((c ^ (col & 7)) << 3);
    bDst[l] = (l * 512 + wid * 64) * 16;
  }

  // ---- frag read offsets (with matching XOR swizzle) ----
  const int rA  = wr * 64 + (lane & 15);      // row within A tile
  const int cBt = wc * 80 + (lane & 15);      // col within B tile
  int ksw[2];
  #pragma unroll
  for (int s = 0; s < 2; s++)
    ksw[s] = ((s * 4 + (lane >> 4)) ^ (lane & 7)) << 4;

  floatx4 acc[4][5];
  #pragma unroll
  for (int m = 0; m < 4; m++)
    #pragma unroll
    for (int n = 0; n < 5; n++)
      #pragma unroll
      for (int q = 0; q < 4; q++) acc[m][n][q] = 0.f;

  // ---- prologue: stage tile 0 ----
  #pragma unroll
  for (int l = 0; l < 2; l++) gload16(aSrc[l], lds + aDst[l]);
  #pragma unroll
  for (int l = 0; l < 5; l++) gload16(bSrc[l], lds + 32768 + bDst[l]);
  __syncthreads();

  #pragma unroll
  for (int t = 0; t < 5; t++){
    const int cur = t & 1;
    if (t < 4){                   // issue next-tile DMA into the other buffer
      const int nb = cur ^ 1;
      #pragma unroll
      for (int l = 0; l < 2; l++) gload16(aSrc[l] + (t + 1) * 64, lds + nb * 16384 + aDst[l]);
      #pragma unroll
      for (int l = 0; l < 5; l++) gload16(bSrc[l] + (t + 1) * 64, lds + 32768 + nb * 40960 + bDst[l]);
    }
    const char* bA = lds + cur * 16384;
    const char* bB = lds + 32768 + cur * 40960;
    #pragma unroll
    for (int s = 0; s < 2; s++){
      short8 af[4], bf[5];
      #pragma unroll
      for (int m = 0; m < 4; m++)
        af[m] = *(const short8*)(bA + (rA + m * 16) * 128 + ksw[s]);
      #pragma unroll
      for (int n = 0; n < 5; n++)
        bf[n] = *(const short8*)(bB + (cBt + n * 16) * 128 + ksw[s]);
      #pragma unroll
      for (int m = 0; m < 4; m++)
        #pragma unroll
        for (int n = 0; n < 5; n++)
          acc[m][n] = __builtin_amdgcn_mfma_f32_16x16x32_bf16(af[m], bf[n], acc[m][n], 0, 0, 0);
    }
    __syncthreads();              // drains vmcnt(0): stage(t+1) landed long ago
  }

  // ---- epilogue: D[row][col]: col = lane&15, row = (lane>>4)*4 + reg ----
  const int colbase = wc * 80 + (lane & 15);
  const long rowb   = tileRow + wr * 64 + ((lane >> 4) << 2);
  #pragma unroll
  for (int m = 0; m < 4; m++){
    #pragma unroll
    for (int n = 0; n < 5; n++){
      const int gcol = colbase + n * 16;
      if (gcol < 300){
        const float bv = bias[gcol];
        #pragma unroll
        for (int r = 0; r < 4; r++){
          const long grow = rowb + m * 16 + r;
          float v = acc[m][n][r];
          v = (mode == 0) ? (fmaxf(v, 0.f) + bv) * scale : tanh_fast(v) + bv;
          C[grow * 300 + gcol] = f2bf(v);
        }
      }
    }
  }
}

// ---------------- gate MLP helper -------------------------------------------
__device__ __forceinline__ float gate_eval(
    float p0, float p1, float p2, float p3, float p4,
    const float W1[3][5], const float W2[3], const float B1[3], float B2)
{
  float acc2 = B2;
  #pragma unroll
  for (int t = 0; t < 3; t++){
    float u = W1[t][0]*p0 + W1[t][1]*p1 + W1[t][2]*p2 + W1[t][3]*p3 + W1[t][4]*p4 + B1[t];
    acc2 += W2[t] * fmaxf(u, 0.f);
  }
  return fmaxf(acc2, 0.f);
}

// ---------------- S1: per-chunk scan composites (40 chunks of 25) -----------
// Rolling v1/v2/v3: reload only when the source row changes (13/7/3 reloads
// per 25 iters instead of 25 each).  Divergent-lane safety: lanes whose
// index didn't change keep their (correct) stale register.
__global__ void k_scan1(const u16* __restrict__ t0, const u16* __restrict__ t1,
    const u16* __restrict__ t2, const u16* __restrict__ t3, const u16* __restrict__ t4,
    const u16* __restrict__ z,
    const float* __restrict__ w1, const float* __restrict__ b1,
    const float* __restrict__ w2, const float* __restrict__ b2,
    float* __restrict__ cA, float* __restrict__ cB, int total)
{
  int i = blockIdx.x * blockDim.x + threadIdx.x;
  if (i >= total) return;
  int d4 = i % 75; int rest = i / 75; int ch = rest % 40; int b = rest / 40;
  const int d = d4 * 4;
  float W1[3][5], W2[3], B1[3][4], B2[4];
  #pragma unroll
  for (int t = 0; t < 3; t++){
    #pragma unroll
    for (int s = 0; s < 5; s++) W1[t][s] = w1[t * 5 + s];
    W2[t] = w2[t];
    #pragma unroll
    for (int q = 0; q < 4; q++) B1[t][q] = b1[t * 300 + d + q];
  }
  #pragma unroll
  for (int q = 0; q < 4; q++) B2[q] = b2[d + q];
  float Ac[4] = {1.f,1.f,1.f,1.f}, Bc[4] = {0.f,0.f,0.f,0.f};
  const int l0 = ch * 25;
  const u16x4 v4 = *(const u16x4*)(t4 + (size_t)(b * 40 + ch) * 300 + d);  // l/25 == ch
  int p1 = -1, p2 = -1, p3 = -1;
  u16x4 v1, v2, v3;
  for (int l = l0; l < l0 + 25; l++){
    u16x4 v0 = *(const u16x4*)(t0 + (size_t)(b * 1000 + l) * 300 + d);
    const int i1 = l >> 1, i2 = l >> 2, i3 = l / 10;
    if (i1 != p1){ p1 = i1; v1 = *(const u16x4*)(t1 + (size_t)(b * 500 + i1) * 300 + d); }
    if (i2 != p2){ p2 = i2; v2 = *(const u16x4*)(t2 + (size_t)(b * 250 + i2) * 300 + d); }
    if (i3 != p3){ p3 = i3; v3 = *(const u16x4*)(t3 + (size_t)(b * 100 + i3) * 300 + d); }
    u16x4 vz = *(const u16x4*)(z + (size_t)(b * 1000 + l) * 300 + d);
    #pragma unroll
    for (int q = 0; q < 4; q++){
      float B1q[3] = {B1[0][q], B1[1][q], B1[2][q]};
      float g  = gate_eval(bf2f(v0[q]), bf2f(v1[q]), bf2f(v2[q]), bf2f(v3[q]), bf2f(v4[q]),
                           W1, W2, B1q, B2[q]);
      Ac[q] = g * Ac[q];
      Bc[q] = g * Bc[q] + (1.f - g) * bf2f(vz[q]);
    }
  }
  *(float4*)(cA + (size_t)ch * 19200 + b * 300 + d) = make_float4(Ac[0], Ac[1], Ac[2], Ac[3]);
  *(float4*)(cB + (size_t)ch * 19200 + b * 300 + d) = make_float4(Bc[0], Bc[1], Bc[2], Bc[3]);
}

// ---------------- S2: combine 40 chunk composites -> chunk-initial c --------
__global__ void k_scan2(const float* __restrict__ cA, const float* __restrict__ cB,
                        float* __restrict__ cinit, int total){
  int i = blockIdx.x * blockDim.x + threadIdx.x;
  if (i >= total) return;
  float c = 0.f;
  for (int ch = 0; ch < 40; ch++){
    cinit[ch * 19200 + i] = c;
    c = cA[ch * 19200 + i] * c + cB[ch * 19200 + i];
  }
}

// ---------------- S3: final scan + output h = o*c (rolling v1/v2/v3) --------
__global__ void k_scan3(const u16* __restrict__ t0, const u16* __restrict__ t1,
    const u16* __restrict__ t2, const u16* __restrict__ t3, const u16* __restrict__ t4,
    const u16* __restrict__ z, const u16* __restrict__ o,
    const float* __restrict__ cinit,
    const float* __restrict__ w1, const float* __restrict__ b1,
    const float* __restrict__ w2, const float* __restrict__ b2,
    float* __restrict__ out, int total)
{
  int i = blockIdx.x * blockDim.x + threadIdx.x;
  if (i >= total) return;
  int d4 = i % 75; int rest = i / 75; int ch = rest % 40; int b = rest / 40;
  const int d = d4 * 4;
  float W1[3][5], W2[3], B1[3][4], B2[4];
  #pragma unroll
  for (int t = 0; t < 3; t++){
    #pragma unroll
    for (int s = 0; s < 5; s++) W1[t][s] = w1[t * 5 + s];
    W2[t] = w2[t];
    #pragma unroll
    for (int q = 0; q < 4; q++) B1[t][q] = b1[t * 300 + d + q];
  }
  #pragma unroll
  for (int q = 0; q < 4; q++) B2[q] = b2[d + q];
  float c[4];
  {
    float4 ci = *(const float4*)(cinit + (size_t)ch * 19200 + b * 300 + d);
    c[0] = ci.x; c[1] = ci.y; c[2] = ci.z; c[3] = ci.w;
  }
  const int l0 = ch * 25;
  const u16x4 v4 = *(const u16x4*)(t4 + (size_t)(b * 40 + ch) * 300 + d);
  int p1 = -1, p2 = -1, p3 = -1;
  u16x4 v1, v2, v3;
  for (int l = l0; l < l0 + 25; l++){
    u16x4 v0 = *(const u16x4*)(t0 + (size_t)(b * 1000 + l) * 300 + d);
    const int i1 = l >> 1, i2 = l >> 2, i3 = l / 10;
    if (i1 != p1){ p1 = i1; v1 = *(const u16x4*)(t1 + (size_t)(b * 500 + i1) * 300 + d); }
    if (i2 != p2){ p2 = i2; v2 = *(const u16x4*)(t2 + (size_t)(b * 250 + i2) * 300 + d); }
    if (i3 != p3){ p3 = i3; v3 = *(const u16x4*)(t3 + (size_t)(b * 100 + i3) * 300 + d); }
    u16x4 vz = *(const u16x4*)(z + (size_t)(b * 1000 + l) * 300 + d);
    u16x4 vo = *(const u16x4*)(o + (size_t)(b * 1000 + l) * 300 + d);
    float4 res;
    #pragma unroll
    for (int q = 0; q < 4; q++){
      float B1q[3] = {B1[0][q], B1[1][q], B1[2][q]};
      float g  = gate_eval(bf2f(v0[q]), bf2f(v1[q]), bf2f(v2[q]), bf2f(v3[q]), bf2f(v4[q]),
                           W1, W2, B1q, B2[q]);
      c[q] = g * c[q] + (1.f - g) * bf2f(vz[q]);
      ((float*)&res)[q] = bf2f(vo[q]) * c[q];
    }
    *(float4*)(out + (size_t)(b * 1000 + l) * 300 + d) = res;
  }
}

extern "C" void kernel_launch(void* const* d_in, const int* in_sizes, int n_in,
                              void* d_out, int out_size, void* d_ws, size_t ws_size,
                              hipStream_t stream){
  const int*   article = (const int*)  d_in[0];
  const float* emb     = (const float*)d_in[1];
  const float* w_ce    = (const float*)d_in[2];
  const float* b_ce    = (const float*)d_in[3];
  const float* w1      = (const float*)d_in[4];
  const float* b1      = (const float*)d_in[5];
  const float* w2      = (const float*)d_in[6];
  const float* b2      = (const float*)d_in[7];
  const float* wz      = (const float*)d_in[8];
  const float* bz      = (const float*)d_in[9];
  const float* wo      = (const float*)d_in[10];
  const float* bo      = (const float*)d_in[11];
  float* out = (float*)d_out;
  char*  ws  = (char*)d_ws;

  // workspace layout (bytes, all 256-aligned)
  u16* x    = (u16*)(ws + 0UL);          // 64000x320 bf16  = 40,960,000
  u16* s2   = (u16*)(ws + 40960000UL);   // 32000x320       = 20,480,000
  u16* s4   = (u16*)(ws + 61440000UL);   // 16000x320       = 10,240,000
  u16* s10  = (u16*)(ws + 71680000UL);   //  6400x320       =  4,096,000
  u16* s25  = (u16*)(ws + 75776000UL);   //  2560x320       =  1,638,400
  u16* wT   = (u16*)(ws + 77414400UL);   // 7x320x320       =  1,433,600
  u16* t0   = (u16*)(ws + 78848000UL);   // 64000x300       = 38,400,000
  u16* t1   = (u16*)(ws + 117248000UL);  // 32000x300       = 19,200,000
  u16* t2   = (u16*)(ws + 136448000UL);  // 16000x300       =  9,600,000
  u16* t3   = (u16*)(ws + 146048000UL);  //  6400x300       =  3,840,000
  u16* t4   = (u16*)(ws + 149888000UL);  //  2560x300       =  1,536,000
  u16* zb   = (u16*)(ws + 151424000UL);  // 64000x300       = 38,400,000
  u16* ob   = (u16*)(ws + 189824000UL);  // 64000x300       = 38,400,000
  // scan composites live in the s2 region (dead after k_gemm_all):
  float* cA = (float*)(ws + 40960000UL); // 40x19200 f32 = 3,072,000
  float* cB = (float*)(ws + 44032000UL);
  float* ci = (float*)(ws + 47104000UL);
  (void)ws_size; (void)in_sizes; (void)n_in; (void)out_size;

  k_wprep     <<<2800, 256, 0, stream>>>(w_ce, wz, wo, wT, 716800);
  k_gather_seg<<<1000, 256, 0, stream>>>(article, emb, x, s2, s4, s10, 256000);
  k_s25       <<< 800, 256, 0, stream>>>(x, s25, 204800);

  k_gemm_all<<<1957, 512, 0, stream>>>(x, s2, s4, s10, s25, wT,
                                       t0, t1, t2, t3, t4, zb, ob,
                                       b_ce, bz, bo);

  k_scan1<<<750, 256, 0, stream>>>(t0, t1, t2, t3, t4, zb, w1, b1, w2, b2, cA, cB, 192000);
  k_scan2<<< 75, 256, 0, stream>>>(cA, cB, ci, 19200);
  k_scan3<<<750, 256, 0, stream>>>(t0, t1, t2, t3, t4, zb, ob, ci, w1, b1, w2, b2, out, 192000);
}